// Round 1
// baseline (1473091.211 us; speedup 1.0000x reference)
//
#include <hip/hip_runtime.h>

#define SEQ  8192
#define HID  2048
#define INP  1024
#define CONC 3072
#define NBLK 256
#define RPB  8   // rows per block: HID / NBLK

typedef unsigned short u16;

__device__ __forceinline__ u16 f2bf(float f){
  unsigned u = __float_as_uint(f);
  u = (u + 0x7fffu + ((u >> 16) & 1u)) >> 16;
  return (u16)u;
}
__device__ __forceinline__ float bf2f(u16 s){ return __uint_as_float(((unsigned)s) << 16); }
__device__ __forceinline__ float bfl(unsigned p){ return __uint_as_float(p << 16); }
__device__ __forceinline__ float bfh(unsigned p){ return __uint_as_float(p & 0xffff0000u); }

// ---------------------------------------------------------------------------
// Phase 1: U_g[t][i] = sum_k W_g[i][HID+k] * x[t][k] + b_g[i]   (bf16 out)
// Tiled fp32 GEMM, 64(t) x 64(i) tile, BK=16, 256 threads, 4x4 microtile.
// ---------------------------------------------------------------------------
__global__ __launch_bounds__(256) void gru_gemm(
    const float* __restrict__ X,
    const float* __restrict__ Wz, const float* __restrict__ Wr, const float* __restrict__ Wh,
    const float* __restrict__ bz, const float* __restrict__ br, const float* __restrict__ bh,
    u16* __restrict__ Uz, u16* __restrict__ Ur, u16* __restrict__ Uh)
{
  const int g = blockIdx.z;
  const float* W    = (g == 0) ? Wz : (g == 1) ? Wr : Wh;
  const float* bias = (g == 0) ? bz : (g == 1) ? br : bh;
  u16* U            = (g == 0) ? Uz : (g == 1) ? Ur : Uh;

  __shared__ __align__(16) float Xs[16][68];   // [k][t]
  __shared__ __align__(16) float Ws[16][68];   // [k][i]

  const int tid = threadIdx.x;
  const int tx = tid & 15, ty = tid >> 4;
  const int t0 = blockIdx.y * 64, i0 = blockIdx.x * 64;
  const int lrow = tid >> 2, lk = (tid & 3) * 4;

  const float* xsrc = X + (size_t)(t0 + lrow) * INP + lk;
  const float* wsrc = W + (size_t)(i0 + lrow) * CONC + HID + lk;

  float4 acc[4];
  acc[0] = acc[1] = acc[2] = acc[3] = make_float4(0.f, 0.f, 0.f, 0.f);

  for (int k0 = 0; k0 < INP; k0 += 16) {
    float4 xv = *(const float4*)(xsrc + k0);
    float4 wv = *(const float4*)(wsrc + k0);
    Xs[lk + 0][lrow] = xv.x; Xs[lk + 1][lrow] = xv.y;
    Xs[lk + 2][lrow] = xv.z; Xs[lk + 3][lrow] = xv.w;
    Ws[lk + 0][lrow] = wv.x; Ws[lk + 1][lrow] = wv.y;
    Ws[lk + 2][lrow] = wv.z; Ws[lk + 3][lrow] = wv.w;
    __syncthreads();
#pragma unroll
    for (int kk = 0; kk < 16; kk++) {
      float4 xa = *(const float4*)&Xs[kk][ty * 4];
      float4 wb = *(const float4*)&Ws[kk][tx * 4];
      acc[0].x = fmaf(xa.x, wb.x, acc[0].x); acc[0].y = fmaf(xa.x, wb.y, acc[0].y);
      acc[0].z = fmaf(xa.x, wb.z, acc[0].z); acc[0].w = fmaf(xa.x, wb.w, acc[0].w);
      acc[1].x = fmaf(xa.y, wb.x, acc[1].x); acc[1].y = fmaf(xa.y, wb.y, acc[1].y);
      acc[1].z = fmaf(xa.y, wb.z, acc[1].z); acc[1].w = fmaf(xa.y, wb.w, acc[1].w);
      acc[2].x = fmaf(xa.z, wb.x, acc[2].x); acc[2].y = fmaf(xa.z, wb.y, acc[2].y);
      acc[2].z = fmaf(xa.z, wb.z, acc[2].z); acc[2].w = fmaf(xa.z, wb.w, acc[2].w);
      acc[3].x = fmaf(xa.w, wb.x, acc[3].x); acc[3].y = fmaf(xa.w, wb.y, acc[3].y);
      acc[3].z = fmaf(xa.w, wb.z, acc[3].z); acc[3].w = fmaf(xa.w, wb.w, acc[3].w);
    }
    __syncthreads();
  }

  float4 bv = *(const float4*)(bias + i0 + tx * 4);
#pragma unroll
  for (int a = 0; a < 4; a++) {
    float4 v = acc[a];
    v.x += bv.x; v.y += bv.y; v.z += bv.z; v.w += bv.w;
    ushort4 o = make_ushort4(f2bf(v.x), f2bf(v.y), f2bf(v.z), f2bf(v.w));
    *(ushort4*)&U[(size_t)(t0 + ty * 4 + a) * HID + i0 + tx * 4] = o;
  }
}

// ---------------------------------------------------------------------------
// Phase 2: persistent recurrent kernel. 256 blocks x 256 threads, 1 block/CU.
// Block b owns rows [b*8, b*8+8) of Wz/Wr/Wh recurrent halves (bf16 in LDS).
// Two device-wide barriers per step (publish r*h; publish h).
// ---------------------------------------------------------------------------
__global__ __launch_bounds__(256, 1) void gru_rnn(
    const u16* __restrict__ U0, const u16* __restrict__ U1, const u16* __restrict__ U2,
    const float* __restrict__ Wz, const float* __restrict__ Wr, const float* __restrict__ Wh,
    float* __restrict__ h_g, float* __restrict__ rh_g,
    unsigned int* __restrict__ ctrl, float* __restrict__ out)
{
  __shared__ __align__(16) u16  w_s[3][RPB][HID];  // 96 KB, bf16 recurrent weights
  __shared__ __align__(16) float h_s[HID];          // 8 KB
  __shared__ __align__(16) float rh_s[HID];         // 8 KB
  __shared__ __align__(16) float hn_s[RPB];
  __shared__ float z_s[RPB];
  __shared__ u16  u_s[24];

  const int tid  = threadIdx.x;
  const int lane = tid & 63;
  const int wv   = tid >> 6;
  const int b    = blockIdx.x;
  const int i0   = b * RPB;

  // ---- one-time: load recurrent weight rows (cols 0..HID) into LDS as bf16
  {
    const float* Wm[3] = {Wz, Wr, Wh};
    const int c0 = tid * 8;
    for (int m = 0; m < 3; m++) {
      for (int r = 0; r < RPB; r++) {
        const float* src = Wm[m] + (size_t)(i0 + r) * CONC;
        u16* dst = &w_s[m][r][0];
        float4 v0 = *(const float4*)(src + c0);
        float4 v1 = *(const float4*)(src + c0 + 4);
        *(ushort4*)(dst + c0)     = make_ushort4(f2bf(v0.x), f2bf(v0.y), f2bf(v0.z), f2bf(v0.w));
        *(ushort4*)(dst + c0 + 4) = make_ushort4(f2bf(v1.x), f2bf(v1.y), f2bf(v1.z), f2bf(v1.w));
      }
    }
  }

  // ---- U prefetch (threads 0..23: gate = tid>>3, row = tid&7)
  const u16* Ug[3] = {U0, U1, U2};
  const int pg = tid >> 3, pr = tid & 7;
  u16 u_next = 0;
  if (tid < 24) u_next = Ug[pg][(size_t)0 * HID + i0 + pr];

  unsigned int bar = 0;

  for (int t = 0; t < SEQ; ++t) {
    // ---- stage h (agent-scope loads -> LDS)
    {
      const int c0 = tid * 8;
#pragma unroll
      for (int m = 0; m < 8; m++)
        h_s[c0 + m] = __hip_atomic_load(&h_g[c0 + m], __ATOMIC_ACQUIRE, __HIP_MEMORY_SCOPE_AGENT);
    }
    if (tid < 24) u_s[tid] = u_next;
    __syncthreads();
    if (tid < 24) {                       // prefetch next step's U (overlaps whole step)
      const int tn = (t + 1 < SEQ) ? (t + 1) : (SEQ - 1);
      u_next = Ug[pg][(size_t)tn * HID + i0 + pr];
    }

    // ---- phase A: z rows (waves 0,1) and r rows (waves 2,3), one wave per row
    float4 hv[8];
#pragma unroll
    for (int j = 0; j < 8; j++) hv[j] = ((const float4*)h_s)[j * 64 + lane];

#pragma unroll
    for (int q = 0; q < 4; q++) {
      const int rowid = wv * 4 + q;       // 0..15
      const int gate  = rowid >> 3;       // 0=z, 1=r
      const int r     = rowid & 7;
      const u16* wrow = &w_s[gate][r][0];
      float acc = 0.f;
#pragma unroll
      for (int j = 0; j < 8; j++) {
        uint2 p = ((const uint2*)wrow)[j * 64 + lane];   // 4 bf16, contiguous 512B/instr
        float4 hh = hv[j];
        acc = fmaf(bfl(p.x), hh.x, acc);
        acc = fmaf(bfh(p.x), hh.y, acc);
        acc = fmaf(bfl(p.y), hh.z, acc);
        acc = fmaf(bfh(p.y), hh.w, acc);
      }
#pragma unroll
      for (int o = 32; o; o >>= 1) acc += __shfl_xor(acc, o);
      if (lane == 0) {
        const float a = acc + bf2f(u_s[gate * 8 + r]);
        const float s = 1.f / (1.f + __expf(-a));
        const int i = i0 + r;
        if (gate == 0) z_s[r] = s;
        else __hip_atomic_store(&rh_g[i], s * h_s[i], __ATOMIC_RELEASE, __HIP_MEMORY_SCOPE_AGENT);
      }
    }

    // ---- barrier 1 (r*h published)
    __syncthreads();
    bar++;
    if (tid == 0) {
      __hip_atomic_fetch_add(ctrl, 1u, __ATOMIC_ACQ_REL, __HIP_MEMORY_SCOPE_AGENT);
      const unsigned tgt = bar * NBLK;
      while (__hip_atomic_load(ctrl, __ATOMIC_ACQUIRE, __HIP_MEMORY_SCOPE_AGENT) < tgt) {}
    }
    __syncthreads();

    // ---- stage r*h
    {
      const int c0 = tid * 8;
#pragma unroll
      for (int m = 0; m < 8; m++)
        rh_s[c0 + m] = __hip_atomic_load(&rh_g[c0 + m], __ATOMIC_ACQUIRE, __HIP_MEMORY_SCOPE_AGENT);
    }
    __syncthreads();

    // ---- phase B: h~ rows, 2 per wave
    float4 rv[8];
#pragma unroll
    for (int j = 0; j < 8; j++) rv[j] = ((const float4*)rh_s)[j * 64 + lane];

#pragma unroll
    for (int q = 0; q < 2; q++) {
      const int r = wv * 2 + q;
      const u16* wrow = &w_s[2][r][0];
      float acc = 0.f;
#pragma unroll
      for (int j = 0; j < 8; j++) {
        uint2 p = ((const uint2*)wrow)[j * 64 + lane];
        float4 hh = rv[j];
        acc = fmaf(bfl(p.x), hh.x, acc);
        acc = fmaf(bfh(p.x), hh.y, acc);
        acc = fmaf(bfl(p.y), hh.z, acc);
        acc = fmaf(bfh(p.y), hh.w, acc);
      }
#pragma unroll
      for (int o = 32; o; o >>= 1) acc += __shfl_xor(acc, o);
      if (lane == 0) {
        const float a  = acc + bf2f(u_s[16 + r]);
        const float ht = tanhf(a);
        const float z  = z_s[r];
        const int i = i0 + r;
        const float hn = (1.f - z) * h_s[i] + z * ht;
        hn_s[r] = hn;
        __hip_atomic_store(&h_g[i], hn, __ATOMIC_RELEASE, __HIP_MEMORY_SCOPE_AGENT);
      }
    }

    // ---- barrier 2 (h published) + coalesced out-write overlapped with spin
    __syncthreads();
    if (tid < 2) {
      float4 v = ((const float4*)hn_s)[tid];
      *(float4*)&out[(size_t)t * HID + i0 + tid * 4] = v;
      if (t == SEQ - 1)
        *(float4*)&out[(size_t)SEQ * HID + i0 + tid * 4] = v;   // h_final
    }
    bar++;
    if (tid == 0) {
      __hip_atomic_fetch_add(ctrl, 1u, __ATOMIC_ACQ_REL, __HIP_MEMORY_SCOPE_AGENT);
      const unsigned tgt = bar * NBLK;
      while (__hip_atomic_load(ctrl, __ATOMIC_ACQUIRE, __HIP_MEMORY_SCOPE_AGENT) < tgt) {}
    }
    __syncthreads();
  }
}

// ---------------------------------------------------------------------------
extern "C" void kernel_launch(void* const* d_in, const int* in_sizes, int n_in,
                              void* d_out, int out_size, void* d_ws, size_t ws_size,
                              hipStream_t stream)
{
  const float* X  = (const float*)d_in[0];
  const float* Wz = (const float*)d_in[1];
  const float* bz = (const float*)d_in[2];
  const float* Wr = (const float*)d_in[3];
  const float* br = (const float*)d_in[4];
  const float* Wh = (const float*)d_in[5];
  const float* bh = (const float*)d_in[6];
  float* out = (float*)d_out;

  char* ws = (char*)d_ws;
  const size_t SZ_U = (size_t)SEQ * HID * sizeof(u16);   // 32 MB per gate
  u16* Uz = (u16*)(ws);
  u16* Ur = (u16*)(ws + SZ_U);
  u16* Uh = (u16*)(ws + 2 * SZ_U);
  float* h_g  = (float*)(ws + 3 * SZ_U);
  float* rh_g = (float*)(ws + 3 * SZ_U + (size_t)HID * 4);
  unsigned int* ctrl = (unsigned int*)(ws + 3 * SZ_U + (size_t)2 * HID * 4);

  // zero h0, rh, and the barrier counter (ws is re-poisoned each call)
  hipMemsetAsync(ws + 3 * SZ_U, 0, (size_t)2 * HID * 4 + 64, stream);

  gru_gemm<<<dim3(HID / 64, SEQ / 64, 3), 256, 0, stream>>>(
      X, Wz, Wr, Wh, bz, br, bh, Uz, Ur, Uh);

  gru_rnn<<<dim3(NBLK), dim3(256), 0, stream>>>(
      Uz, Ur, Uh, Wz, Wr, Wh, h_g, rh_g, ctrl, out);
}

// Round 2
// 117626.904 us; speedup vs baseline: 12.5234x; 12.5234x over previous
//
#include <hip/hip_runtime.h>

#define SEQ  8192
#define HID  2048
#define INP  1024
#define CONC 3072
#define NBLK 256
#define RPB  8   // rows per block: HID / NBLK

typedef unsigned short u16;

__device__ __forceinline__ u16 f2bf(float f){
  unsigned u = __float_as_uint(f);
  u = (u + 0x7fffu + ((u >> 16) & 1u)) >> 16;
  return (u16)u;
}
__device__ __forceinline__ float bf2f(u16 s){ return __uint_as_float(((unsigned)s) << 16); }
__device__ __forceinline__ float bfl(unsigned p){ return __uint_as_float(p << 16); }
__device__ __forceinline__ float bfh(unsigned p){ return __uint_as_float(p & 0xffff0000u); }

// Coherent (cross-XCD) ops WITHOUT cache maintenance: relaxed agent-scope
// atomics compile to global_load/store ... sc0 sc1 — they bypass stale L1/L2
// and hit the Infinity-Cache coherent point, no buffer_wbl2/buffer_inv.
__device__ __forceinline__ float cload(const float* p){
  return __hip_atomic_load(p, __ATOMIC_RELAXED, __HIP_MEMORY_SCOPE_AGENT);
}
__device__ __forceinline__ void cstore(float* p, float v){
  __hip_atomic_store(p, v, __ATOMIC_RELAXED, __HIP_MEMORY_SCOPE_AGENT);
}

// ---------------------------------------------------------------------------
// Phase 1: U_g[t][i] = sum_k W_g[i][HID+k] * x[t][k] + b_g[i]   (bf16 out)
// ---------------------------------------------------------------------------
__global__ __launch_bounds__(256) void gru_gemm(
    const float* __restrict__ X,
    const float* __restrict__ Wz, const float* __restrict__ Wr, const float* __restrict__ Wh,
    const float* __restrict__ bz, const float* __restrict__ br, const float* __restrict__ bh,
    u16* __restrict__ Uz, u16* __restrict__ Ur, u16* __restrict__ Uh)
{
  const int g = blockIdx.z;
  const float* W    = (g == 0) ? Wz : (g == 1) ? Wr : Wh;
  const float* bias = (g == 0) ? bz : (g == 1) ? br : bh;
  u16* U            = (g == 0) ? Uz : (g == 1) ? Ur : Uh;

  __shared__ __align__(16) float Xs[16][68];   // [k][t]
  __shared__ __align__(16) float Ws[16][68];   // [k][i]

  const int tid = threadIdx.x;
  const int tx = tid & 15, ty = tid >> 4;
  const int t0 = blockIdx.y * 64, i0 = blockIdx.x * 64;
  const int lrow = tid >> 2, lk = (tid & 3) * 4;

  const float* xsrc = X + (size_t)(t0 + lrow) * INP + lk;
  const float* wsrc = W + (size_t)(i0 + lrow) * CONC + HID + lk;

  float4 acc[4];
  acc[0] = acc[1] = acc[2] = acc[3] = make_float4(0.f, 0.f, 0.f, 0.f);

  for (int k0 = 0; k0 < INP; k0 += 16) {
    float4 xv = *(const float4*)(xsrc + k0);
    float4 wv = *(const float4*)(wsrc + k0);
    Xs[lk + 0][lrow] = xv.x; Xs[lk + 1][lrow] = xv.y;
    Xs[lk + 2][lrow] = xv.z; Xs[lk + 3][lrow] = xv.w;
    Ws[lk + 0][lrow] = wv.x; Ws[lk + 1][lrow] = wv.y;
    Ws[lk + 2][lrow] = wv.z; Ws[lk + 3][lrow] = wv.w;
    __syncthreads();
#pragma unroll
    for (int kk = 0; kk < 16; kk++) {
      float4 xa = *(const float4*)&Xs[kk][ty * 4];
      float4 wb = *(const float4*)&Ws[kk][tx * 4];
      acc[0].x = fmaf(xa.x, wb.x, acc[0].x); acc[0].y = fmaf(xa.x, wb.y, acc[0].y);
      acc[0].z = fmaf(xa.x, wb.z, acc[0].z); acc[0].w = fmaf(xa.x, wb.w, acc[0].w);
      acc[1].x = fmaf(xa.y, wb.x, acc[1].x); acc[1].y = fmaf(xa.y, wb.y, acc[1].y);
      acc[1].z = fmaf(xa.y, wb.z, acc[1].z); acc[1].w = fmaf(xa.y, wb.w, acc[1].w);
      acc[2].x = fmaf(xa.z, wb.x, acc[2].x); acc[2].y = fmaf(xa.z, wb.y, acc[2].y);
      acc[2].z = fmaf(xa.z, wb.z, acc[2].z); acc[2].w = fmaf(xa.z, wb.w, acc[2].w);
      acc[3].x = fmaf(xa.w, wb.x, acc[3].x); acc[3].y = fmaf(xa.w, wb.y, acc[3].y);
      acc[3].z = fmaf(xa.w, wb.z, acc[3].z); acc[3].w = fmaf(xa.w, wb.w, acc[3].w);
    }
    __syncthreads();
  }

  float4 bv = *(const float4*)(bias + i0 + tx * 4);
#pragma unroll
  for (int a = 0; a < 4; a++) {
    float4 v = acc[a];
    v.x += bv.x; v.y += bv.y; v.z += bv.z; v.w += bv.w;
    ushort4 o = make_ushort4(f2bf(v.x), f2bf(v.y), f2bf(v.z), f2bf(v.w));
    *(ushort4*)&U[(size_t)(t0 + ty * 4 + a) * HID + i0 + tx * 4] = o;
  }
}

// ---------------------------------------------------------------------------
// Phase 2: persistent recurrent kernel. 256 blocks x 256 threads, 1 block/CU.
// All cross-block traffic = relaxed agent atomics (sc0 sc1, no cache flush).
// Ordering: per-wave s_waitcnt vmcnt(0) before the barrier signal.
// ---------------------------------------------------------------------------
__global__ __launch_bounds__(256, 1) void gru_rnn(
    const u16* __restrict__ U0, const u16* __restrict__ U1, const u16* __restrict__ U2,
    const float* __restrict__ Wz, const float* __restrict__ Wr, const float* __restrict__ Wh,
    float* __restrict__ h_g, float* __restrict__ rh_g,
    unsigned int* __restrict__ ctrl, float* __restrict__ out)
{
  __shared__ __align__(16) u16  w_s[3][RPB][HID];  // 96 KB bf16 recurrent weights
  __shared__ __align__(16) float h_s[HID];          // 8 KB
  __shared__ __align__(16) float rh_s[HID];         // 8 KB
  __shared__ __align__(16) float hn_s[RPB];
  __shared__ u16  u_s[24];

  const int tid  = threadIdx.x;
  const int lane = tid & 63;
  const int wv   = tid >> 6;
  const int b    = blockIdx.x;
  const int i0   = b * RPB;

  // ---- one-time: recurrent weight rows (cols 0..HID) into LDS as bf16
  {
    const float* Wm[3] = {Wz, Wr, Wh};
    const int c0 = tid * 8;
    for (int m = 0; m < 3; m++) {
      for (int r = 0; r < RPB; r++) {
        const float* src = Wm[m] + (size_t)(i0 + r) * CONC;
        u16* dst = &w_s[m][r][0];
        float4 v0 = *(const float4*)(src + c0);
        float4 v1 = *(const float4*)(src + c0 + 4);
        *(ushort4*)(dst + c0)     = make_ushort4(f2bf(v0.x), f2bf(v0.y), f2bf(v0.z), f2bf(v0.w));
        *(ushort4*)(dst + c0 + 4) = make_ushort4(f2bf(v1.x), f2bf(v1.y), f2bf(v1.z), f2bf(v1.w));
      }
    }
  }

  // ---- U prefetch (threads 0..23: gate = tid>>3, row = tid&7)
  const u16* Ug[3] = {U0, U1, U2};
  const int pg = tid >> 3, pr = tid & 7;
  u16 u_next = 0;
  if (tid < 24) u_next = Ug[pg][(size_t)0 * HID + i0 + pr];

  unsigned int bar = 0;
  float z_reg[2] = {0.f, 0.f};
  const int c0 = tid * 8;

  for (int t = 0; t < SEQ; ++t) {
    // ---- stage h (coherent loads -> LDS)
    {
      float hv8[8];
#pragma unroll
      for (int m = 0; m < 8; m++) hv8[m] = cload(&h_g[c0 + m]);
#pragma unroll
      for (int m = 0; m < 8; m++) h_s[c0 + m] = hv8[m];
    }
    if (tid < 24) u_s[tid] = u_next;
    __syncthreads();
    if (tid < 24) {                       // prefetch next step's U
      const int tn = (t + 1 < SEQ) ? (t + 1) : (SEQ - 1);
      u_next = Ug[pg][(size_t)tn * HID + i0 + pr];
    }

    // ---- phase A: r rows first (q=0,1: publish early), then z rows (q=2,3)
    float4 hv[8];
#pragma unroll
    for (int j = 0; j < 8; j++) hv[j] = ((const float4*)h_s)[j * 64 + lane];

#pragma unroll
    for (int q = 0; q < 4; q++) {
      const int gate = (q < 2) ? 1 : 0;   // 1=r (first), 0=z
      const int r    = wv * 2 + (q & 1);
      const u16* wrow = &w_s[gate][r][0];
      float acc = 0.f;
#pragma unroll
      for (int j = 0; j < 8; j++) {
        uint2 p = ((const uint2*)wrow)[j * 64 + lane];
        float4 hh = hv[j];
        acc = fmaf(bfl(p.x), hh.x, acc);
        acc = fmaf(bfh(p.x), hh.y, acc);
        acc = fmaf(bfl(p.y), hh.z, acc);
        acc = fmaf(bfh(p.y), hh.w, acc);
      }
#pragma unroll
      for (int o = 32; o; o >>= 1) acc += __shfl_xor(acc, o);
      if (lane == 0) {
        const float a = acc + bf2f(u_s[gate * 8 + r]);
        const float s = 1.f / (1.f + __expf(-a));
        if (gate == 1) cstore(&rh_g[i0 + r], s * h_s[i0 + r]);
        else           z_reg[q - 2] = s;  // stays in lane 0's registers
      }
    }

    // ---- barrier 1: rh published
    asm volatile("s_waitcnt vmcnt(0)" ::: "memory");  // per-wave: rh stores at coherent point
    __syncthreads();
    bar++;
    if (tid == 0) {
      __hip_atomic_fetch_add(ctrl, 1u, __ATOMIC_RELAXED, __HIP_MEMORY_SCOPE_AGENT);
      const unsigned tgt = bar * NBLK;
      while (__hip_atomic_load(ctrl, __ATOMIC_RELAXED, __HIP_MEMORY_SCOPE_AGENT) < tgt)
        __builtin_amdgcn_s_sleep(1);
    }
    asm volatile("" ::: "memory");
    __syncthreads();

    // ---- stage rh
    {
      float rv8[8];
#pragma unroll
      for (int m = 0; m < 8; m++) rv8[m] = cload(&rh_g[c0 + m]);
#pragma unroll
      for (int m = 0; m < 8; m++) rh_s[c0 + m] = rv8[m];
    }
    __syncthreads();

    // ---- phase B: h~ rows, 2 per wave (same rows as this wave's z rows)
    float4 rv[8];
#pragma unroll
    for (int j = 0; j < 8; j++) rv[j] = ((const float4*)rh_s)[j * 64 + lane];

#pragma unroll
    for (int q = 0; q < 2; q++) {
      const int r = wv * 2 + q;
      const u16* wrow = &w_s[2][r][0];
      float acc = 0.f;
#pragma unroll
      for (int j = 0; j < 8; j++) {
        uint2 p = ((const uint2*)wrow)[j * 64 + lane];
        float4 hh = rv[j];
        acc = fmaf(bfl(p.x), hh.x, acc);
        acc = fmaf(bfh(p.x), hh.y, acc);
        acc = fmaf(bfl(p.y), hh.z, acc);
        acc = fmaf(bfh(p.y), hh.w, acc);
      }
#pragma unroll
      for (int o = 32; o; o >>= 1) acc += __shfl_xor(acc, o);
      if (lane == 0) {
        const float a  = acc + bf2f(u_s[16 + r]);
        const float ht = tanhf(a);
        const float z  = z_reg[q];
        const int i = i0 + r;
        const float hn = (1.f - z) * h_s[i] + z * ht;
        hn_s[r] = hn;
        cstore(&h_g[i], hn);
      }
    }

    // ---- barrier 2: h published; out-write overlaps the spin
    asm volatile("s_waitcnt vmcnt(0)" ::: "memory");  // per-wave: h stores at coherent point
    __syncthreads();                                   // also makes hn_s visible
    bar++;
    if (tid == 0)
      __hip_atomic_fetch_add(ctrl, 1u, __ATOMIC_RELAXED, __HIP_MEMORY_SCOPE_AGENT);
    if (tid < 2) {                                     // plain stores; only host reads out
      float4 v = ((const float4*)hn_s)[tid];
      *(float4*)&out[(size_t)t * HID + i0 + tid * 4] = v;
      if (t == SEQ - 1)
        *(float4*)&out[(size_t)SEQ * HID + i0 + tid * 4] = v;   // h_final
    }
    if (tid == 0) {
      const unsigned tgt = bar * NBLK;
      while (__hip_atomic_load(ctrl, __ATOMIC_RELAXED, __HIP_MEMORY_SCOPE_AGENT) < tgt)
        __builtin_amdgcn_s_sleep(1);
    }
    asm volatile("" ::: "memory");
    __syncthreads();
  }
}

// ---------------------------------------------------------------------------
extern "C" void kernel_launch(void* const* d_in, const int* in_sizes, int n_in,
                              void* d_out, int out_size, void* d_ws, size_t ws_size,
                              hipStream_t stream)
{
  const float* X  = (const float*)d_in[0];
  const float* Wz = (const float*)d_in[1];
  const float* bz = (const float*)d_in[2];
  const float* Wr = (const float*)d_in[3];
  const float* br = (const float*)d_in[4];
  const float* Wh = (const float*)d_in[5];
  const float* bh = (const float*)d_in[6];
  float* out = (float*)d_out;

  char* ws = (char*)d_ws;
  const size_t SZ_U = (size_t)SEQ * HID * sizeof(u16);   // 32 MB per gate
  u16* Uz = (u16*)(ws);
  u16* Ur = (u16*)(ws + SZ_U);
  u16* Uh = (u16*)(ws + 2 * SZ_U);
  float* h_g  = (float*)(ws + 3 * SZ_U);
  float* rh_g = (float*)(ws + 3 * SZ_U + (size_t)HID * 4);
  unsigned int* ctrl = (unsigned int*)(ws + 3 * SZ_U + (size_t)2 * HID * 4);

  // zero h0, rh, and the barrier counter (ws is re-poisoned each call)
  hipMemsetAsync(ws + 3 * SZ_U, 0, (size_t)2 * HID * 4 + 64, stream);

  gru_gemm<<<dim3(HID / 64, SEQ / 64, 3), 256, 0, stream>>>(
      X, Wz, Wr, Wh, bz, br, bh, Uz, Ur, Uh);

  gru_rnn<<<dim3(NBLK), dim3(256), 0, stream>>>(
      Uz, Ur, Uh, Wz, Wr, Wh, h_g, rh_g, ctrl, out);
}

// Round 3
// 85948.663 us; speedup vs baseline: 17.1392x; 1.3686x over previous
//
#include <hip/hip_runtime.h>

#define SEQ  8192
#define HID  2048
#define INP  1024
#define CONC 3072
#define NBLK 256
#define RPB  8   // rows per block: HID / NBLK

typedef unsigned short u16;

__device__ __forceinline__ u16 f2bf(float f){
  unsigned u = __float_as_uint(f);
  u = (u + 0x7fffu + ((u >> 16) & 1u)) >> 16;
  return (u16)u;
}
__device__ __forceinline__ float bf2f(u16 s){ return __uint_as_float(((unsigned)s) << 16); }
__device__ __forceinline__ float bfl(unsigned p){ return __uint_as_float(p << 16); }
__device__ __forceinline__ float bfh(unsigned p){ return __uint_as_float(p & 0xffff0000u); }

// Relaxed agent-scope ops: coherent-point (Infinity Cache) access, no cache
// maintenance (no buffer_wbl2 / buffer_inv).
__device__ __forceinline__ float cload(const float* p){
  return __hip_atomic_load(p, __ATOMIC_RELAXED, __HIP_MEMORY_SCOPE_AGENT);
}
__device__ __forceinline__ void cstore(float* p, float v){
  __hip_atomic_store(p, v, __ATOMIC_RELAXED, __HIP_MEMORY_SCOPE_AGENT);
}
__device__ __forceinline__ unsigned cloadu(const unsigned* p){
  return __hip_atomic_load(p, __ATOMIC_RELAXED, __HIP_MEMORY_SCOPE_AGENT);
}
__device__ __forceinline__ void cstoreu(unsigned* p, unsigned v){
  __hip_atomic_store(p, v, __ATOMIC_RELAXED, __HIP_MEMORY_SCOPE_AGENT);
}

// ---------------------------------------------------------------------------
// Phase 1: U_g[t][i] = sum_k W_g[i][HID+k] * x[t][k] + b_g[i]   (bf16 out)
// ---------------------------------------------------------------------------
__global__ __launch_bounds__(256) void gru_gemm(
    const float* __restrict__ X,
    const float* __restrict__ Wz, const float* __restrict__ Wr, const float* __restrict__ Wh,
    const float* __restrict__ bz, const float* __restrict__ br, const float* __restrict__ bh,
    u16* __restrict__ Uz, u16* __restrict__ Ur, u16* __restrict__ Uh)
{
  const int g = blockIdx.z;
  const float* W    = (g == 0) ? Wz : (g == 1) ? Wr : Wh;
  const float* bias = (g == 0) ? bz : (g == 1) ? br : bh;
  u16* U            = (g == 0) ? Uz : (g == 1) ? Ur : Uh;

  __shared__ __align__(16) float Xs[16][68];   // [k][t]
  __shared__ __align__(16) float Ws[16][68];   // [k][i]

  const int tid = threadIdx.x;
  const int tx = tid & 15, ty = tid >> 4;
  const int t0 = blockIdx.y * 64, i0 = blockIdx.x * 64;
  const int lrow = tid >> 2, lk = (tid & 3) * 4;

  const float* xsrc = X + (size_t)(t0 + lrow) * INP + lk;
  const float* wsrc = W + (size_t)(i0 + lrow) * CONC + HID + lk;

  float4 acc[4];
  acc[0] = acc[1] = acc[2] = acc[3] = make_float4(0.f, 0.f, 0.f, 0.f);

  for (int k0 = 0; k0 < INP; k0 += 16) {
    float4 xv = *(const float4*)(xsrc + k0);
    float4 wv = *(const float4*)(wsrc + k0);
    Xs[lk + 0][lrow] = xv.x; Xs[lk + 1][lrow] = xv.y;
    Xs[lk + 2][lrow] = xv.z; Xs[lk + 3][lrow] = xv.w;
    Ws[lk + 0][lrow] = wv.x; Ws[lk + 1][lrow] = wv.y;
    Ws[lk + 2][lrow] = wv.z; Ws[lk + 3][lrow] = wv.w;
    __syncthreads();
#pragma unroll
    for (int kk = 0; kk < 16; kk++) {
      float4 xa = *(const float4*)&Xs[kk][ty * 4];
      float4 wb = *(const float4*)&Ws[kk][tx * 4];
      acc[0].x = fmaf(xa.x, wb.x, acc[0].x); acc[0].y = fmaf(xa.x, wb.y, acc[0].y);
      acc[0].z = fmaf(xa.x, wb.z, acc[0].z); acc[0].w = fmaf(xa.x, wb.w, acc[0].w);
      acc[1].x = fmaf(xa.y, wb.x, acc[1].x); acc[1].y = fmaf(xa.y, wb.y, acc[1].y);
      acc[1].z = fmaf(xa.y, wb.z, acc[1].z); acc[1].w = fmaf(xa.y, wb.w, acc[1].w);
      acc[2].x = fmaf(xa.z, wb.x, acc[2].x); acc[2].y = fmaf(xa.z, wb.y, acc[2].y);
      acc[2].z = fmaf(xa.z, wb.z, acc[2].z); acc[2].w = fmaf(xa.z, wb.w, acc[2].w);
      acc[3].x = fmaf(xa.w, wb.x, acc[3].x); acc[3].y = fmaf(xa.w, wb.y, acc[3].y);
      acc[3].z = fmaf(xa.w, wb.z, acc[3].z); acc[3].w = fmaf(xa.w, wb.w, acc[3].w);
    }
    __syncthreads();
  }

  float4 bv = *(const float4*)(bias + i0 + tx * 4);
#pragma unroll
  for (int a = 0; a < 4; a++) {
    float4 v = acc[a];
    v.x += bv.x; v.y += bv.y; v.z += bv.z; v.w += bv.w;
    ushort4 o = make_ushort4(f2bf(v.x), f2bf(v.y), f2bf(v.z), f2bf(v.w));
    *(ushort4*)&U[(size_t)(t0 + ty * 4 + a) * HID + i0 + tx * 4] = o;
  }
}

// ---------------------------------------------------------------------------
// Phase 2: persistent recurrent kernel, dataflow sync (no global barrier).
// Producer block b publishes its 8 h (or rh) values, then sets flag[b]=t+1.
// Consumer thread tid waits only on flag[tid], then loads those 8 values.
// h_g / rh_g double-buffered by step parity; per-thread polls bound drift <1
// step, so buffer overwrite is race-free.
// ---------------------------------------------------------------------------
__global__ __launch_bounds__(256, 1) void gru_rnn(
    const u16* __restrict__ U0, const u16* __restrict__ U1, const u16* __restrict__ U2,
    const float* __restrict__ Wz, const float* __restrict__ Wr, const float* __restrict__ Wh,
    float* __restrict__ h_g, float* __restrict__ rh_g,
    unsigned* __restrict__ hflag, unsigned* __restrict__ rhflag,
    float* __restrict__ out)
{
  __shared__ __align__(16) u16  w_s[3][RPB][HID];  // 96 KB bf16 recurrent weights
  __shared__ __align__(16) float h_s[HID];          // 8 KB
  __shared__ __align__(16) float rh_s[HID];         // 8 KB
  __shared__ __align__(16) float hn_s[RPB];
  __shared__ u16  u_s[24];

  const int tid  = threadIdx.x;
  const int lane = tid & 63;
  const int wv   = tid >> 6;
  const int b    = blockIdx.x;
  const int i0   = b * RPB;

  // ---- one-time: recurrent weight rows (cols 0..HID) into LDS as bf16
  {
    const float* Wm[3] = {Wz, Wr, Wh};
    const int c0 = tid * 8;
    for (int m = 0; m < 3; m++) {
      for (int r = 0; r < RPB; r++) {
        const float* src = Wm[m] + (size_t)(i0 + r) * CONC;
        u16* dst = &w_s[m][r][0];
        float4 v0 = *(const float4*)(src + c0);
        float4 v1 = *(const float4*)(src + c0 + 4);
        *(ushort4*)(dst + c0)     = make_ushort4(f2bf(v0.x), f2bf(v0.y), f2bf(v0.z), f2bf(v0.w));
        *(ushort4*)(dst + c0 + 4) = make_ushort4(f2bf(v1.x), f2bf(v1.y), f2bf(v1.z), f2bf(v1.w));
      }
    }
  }

  // ---- U prefetch (threads 0..23: gate = tid>>3, row = tid&7)
  const u16* Ug[3] = {U0, U1, U2};
  const int pg = tid >> 3, pr = tid & 7;
  u16 u_next = 0;
  if (tid < 24) u_next = Ug[pg][(size_t)0 * HID + i0 + pr];

  float z_reg[2] = {0.f, 0.f};
  const int c0 = tid * 8;

  for (int t = 0; t < SEQ; ++t) {
    const float* hsrc = h_g + (size_t)(t & 1) * HID;         // h_{t-1}
    float*       hdst = h_g + (size_t)((t + 1) & 1) * HID;   // h_t
    float*       rhb  = rh_g + (size_t)(t & 1) * HID;

    // ---- stage h: wait for producer of words [tid*8, tid*8+8), then load
    while (cloadu(&hflag[tid]) < (unsigned)t) __builtin_amdgcn_s_sleep(1);
    asm volatile("" ::: "memory");
    {
      float hv8[8];
#pragma unroll
      for (int m = 0; m < 8; m++) hv8[m] = cload(&hsrc[c0 + m]);
#pragma unroll
      for (int m = 0; m < 8; m++) h_s[c0 + m] = hv8[m];
    }
    if (tid < 24) u_s[tid] = u_next;
    __syncthreads();
    if (tid < 24) {                       // prefetch next step's U
      const int tn = (t + 1 < SEQ) ? (t + 1) : (SEQ - 1);
      u_next = Ug[pg][(size_t)tn * HID + i0 + pr];
    }

    float4 hv[8];
#pragma unroll
    for (int j = 0; j < 8; j++) hv[j] = ((const float4*)h_s)[j * 64 + lane];

    // ---- r rows (2 per wave), publish rh early
#pragma unroll
    for (int q = 0; q < 2; q++) {
      const int r = wv * 2 + q;
      const u16* wrow = &w_s[1][r][0];
      float acc = 0.f;
#pragma unroll
      for (int j = 0; j < 8; j++) {
        uint2 p = ((const uint2*)wrow)[j * 64 + lane];
        float4 hh = hv[j];
        acc = fmaf(bfl(p.x), hh.x, acc);
        acc = fmaf(bfh(p.x), hh.y, acc);
        acc = fmaf(bfl(p.y), hh.z, acc);
        acc = fmaf(bfh(p.y), hh.w, acc);
      }
#pragma unroll
      for (int o = 32; o; o >>= 1) acc += __shfl_xor(acc, o);
      if (lane == 0) {
        const float a = acc + bf2f(u_s[8 + r]);
        const float s = 1.f / (1.f + __expf(-a));
        cstore(&rhb[i0 + r], s * h_s[i0 + r]);
      }
    }
    asm volatile("s_waitcnt vmcnt(0)" ::: "memory");  // rh at coherent point
    __syncthreads();
    if (tid == 0) cstoreu(&rhflag[b], (unsigned)(t + 1));

    // ---- z rows (overlap the rh round-trip)
#pragma unroll
    for (int q = 0; q < 2; q++) {
      const int r = wv * 2 + q;
      const u16* wrow = &w_s[0][r][0];
      float acc = 0.f;
#pragma unroll
      for (int j = 0; j < 8; j++) {
        uint2 p = ((const uint2*)wrow)[j * 64 + lane];
        float4 hh = hv[j];
        acc = fmaf(bfl(p.x), hh.x, acc);
        acc = fmaf(bfh(p.x), hh.y, acc);
        acc = fmaf(bfl(p.y), hh.z, acc);
        acc = fmaf(bfh(p.y), hh.w, acc);
      }
#pragma unroll
      for (int o = 32; o; o >>= 1) acc += __shfl_xor(acc, o);
      if (lane == 0) {
        const float a = acc + bf2f(u_s[0 + r]);
        z_reg[q] = 1.f / (1.f + __expf(-a));
      }
    }

    // ---- stage rh (dataflow wait on each producer)
    while (cloadu(&rhflag[tid]) < (unsigned)(t + 1)) __builtin_amdgcn_s_sleep(1);
    asm volatile("" ::: "memory");
    {
      float rv8[8];
#pragma unroll
      for (int m = 0; m < 8; m++) rv8[m] = cload(&rhb[c0 + m]);
#pragma unroll
      for (int m = 0; m < 8; m++) rh_s[c0 + m] = rv8[m];
    }
    __syncthreads();

    // ---- phase B: h~ rows, 2 per wave (same rows as this wave's z rows)
    float4 rv[8];
#pragma unroll
    for (int j = 0; j < 8; j++) rv[j] = ((const float4*)rh_s)[j * 64 + lane];

#pragma unroll
    for (int q = 0; q < 2; q++) {
      const int r = wv * 2 + q;
      const u16* wrow = &w_s[2][r][0];
      float acc = 0.f;
#pragma unroll
      for (int j = 0; j < 8; j++) {
        uint2 p = ((const uint2*)wrow)[j * 64 + lane];
        float4 hh = rv[j];
        acc = fmaf(bfl(p.x), hh.x, acc);
        acc = fmaf(bfh(p.x), hh.y, acc);
        acc = fmaf(bfl(p.y), hh.z, acc);
        acc = fmaf(bfh(p.y), hh.w, acc);
      }
#pragma unroll
      for (int o = 32; o; o >>= 1) acc += __shfl_xor(acc, o);
      if (lane == 0) {
        const float a  = acc + bf2f(u_s[16 + r]);
        const float ht = tanhf(a);
        const float z  = z_reg[q];
        const int i = i0 + r;
        const float hn = (1.f - z) * h_s[i] + z * ht;
        hn_s[r] = hn;
        cstore(&hdst[i], hn);
      }
    }
    asm volatile("s_waitcnt vmcnt(0)" ::: "memory");  // h at coherent point
    __syncthreads();                                   // hn_s visible too
    if (tid == 0) cstoreu(&hflag[b], (unsigned)(t + 1));
    if (tid < 2) {                                     // plain stores; host-only reader
      float4 v = ((const float4*)hn_s)[tid];
      *(float4*)&out[(size_t)t * HID + i0 + tid * 4] = v;
      if (t == SEQ - 1)
        *(float4*)&out[(size_t)SEQ * HID + i0 + tid * 4] = v;   // h_final
    }
  }
}

// ---------------------------------------------------------------------------
extern "C" void kernel_launch(void* const* d_in, const int* in_sizes, int n_in,
                              void* d_out, int out_size, void* d_ws, size_t ws_size,
                              hipStream_t stream)
{
  const float* X  = (const float*)d_in[0];
  const float* Wz = (const float*)d_in[1];
  const float* bz = (const float*)d_in[2];
  const float* Wr = (const float*)d_in[3];
  const float* br = (const float*)d_in[4];
  const float* Wh = (const float*)d_in[5];
  const float* bh = (const float*)d_in[6];
  float* out = (float*)d_out;

  char* ws = (char*)d_ws;
  const size_t SZ_U = (size_t)SEQ * HID * sizeof(u16);   // 32 MB per gate
  u16* Uz = (u16*)(ws);
  u16* Ur = (u16*)(ws + SZ_U);
  u16* Uh = (u16*)(ws + 2 * SZ_U);
  float* h_g      = (float*)(ws + 3 * SZ_U);             // [2][HID]
  float* rh_g     = h_g + 2 * HID;                       // [2][HID]
  unsigned* hflag  = (unsigned*)(rh_g + 2 * HID);        // [NBLK]
  unsigned* rhflag = hflag + NBLK;                       // [NBLK]

  // zero h buffers, rh buffers, and both flag arrays
  hipMemsetAsync(ws + 3 * SZ_U, 0, (size_t)4 * HID * 4 + 2 * NBLK * 4, stream);

  gru_gemm<<<dim3(HID / 64, SEQ / 64, 3), 256, 0, stream>>>(
      X, Wz, Wr, Wh, bz, br, bh, Uz, Ur, Uh);

  gru_rnn<<<dim3(NBLK), dim3(256), 0, stream>>>(
      Uz, Ur, Uh, Wz, Wr, Wh, h_g, rh_g, hflag, rhflag, out);
}

// Round 4
// 78637.866 us; speedup vs baseline: 18.7326x; 1.0930x over previous
//
#include <hip/hip_runtime.h>

#define SEQ  8192
#define HID  2048
#define INP  1024
#define CONC 3072
#define NBLK 256
#define RPB  8   // rows per block: HID / NBLK
#define GRP  32  // blocks per flag group
#define NG   8   // number of groups

typedef unsigned short u16;

__device__ __forceinline__ u16 f2bf(float f){
  unsigned u = __float_as_uint(f);
  u = (u + 0x7fffu + ((u >> 16) & 1u)) >> 16;
  return (u16)u;
}
__device__ __forceinline__ float bf2f(u16 s){ return __uint_as_float(((unsigned)s) << 16); }
__device__ __forceinline__ float bfl(unsigned p){ return __uint_as_float(p << 16); }
__device__ __forceinline__ float bfh(unsigned p){ return __uint_as_float(p & 0xffff0000u); }

// Relaxed agent-scope ops: coherent-point (Infinity Cache) access, no cache
// maintenance instructions.
__device__ __forceinline__ float cload(const float* p){
  return __hip_atomic_load(p, __ATOMIC_RELAXED, __HIP_MEMORY_SCOPE_AGENT);
}
__device__ __forceinline__ void cstore(float* p, float v){
  __hip_atomic_store(p, v, __ATOMIC_RELAXED, __HIP_MEMORY_SCOPE_AGENT);
}
__device__ __forceinline__ unsigned cloadu(const unsigned* p){
  return __hip_atomic_load(p, __ATOMIC_RELAXED, __HIP_MEMORY_SCOPE_AGENT);
}
__device__ __forceinline__ void cstoreu(unsigned* p, unsigned v){
  __hip_atomic_store(p, v, __ATOMIC_RELAXED, __HIP_MEMORY_SCOPE_AGENT);
}

// ---------------------------------------------------------------------------
// Phase 1: U_g[t][i] = sum_k W_g[i][HID+k] * x[t][k] + b_g[i]   (bf16 out)
// ---------------------------------------------------------------------------
__global__ __launch_bounds__(256) void gru_gemm(
    const float* __restrict__ X,
    const float* __restrict__ Wz, const float* __restrict__ Wr, const float* __restrict__ Wh,
    const float* __restrict__ bz, const float* __restrict__ br, const float* __restrict__ bh,
    u16* __restrict__ Uz, u16* __restrict__ Ur, u16* __restrict__ Uh)
{
  const int g = blockIdx.z;
  const float* W    = (g == 0) ? Wz : (g == 1) ? Wr : Wh;
  const float* bias = (g == 0) ? bz : (g == 1) ? br : bh;
  u16* U            = (g == 0) ? Uz : (g == 1) ? Ur : Uh;

  __shared__ __align__(16) float Xs[16][68];   // [k][t]
  __shared__ __align__(16) float Ws[16][68];   // [k][i]

  const int tid = threadIdx.x;
  const int tx = tid & 15, ty = tid >> 4;
  const int t0 = blockIdx.y * 64, i0 = blockIdx.x * 64;
  const int lrow = tid >> 2, lk = (tid & 3) * 4;

  const float* xsrc = X + (size_t)(t0 + lrow) * INP + lk;
  const float* wsrc = W + (size_t)(i0 + lrow) * CONC + HID + lk;

  float4 acc[4];
  acc[0] = acc[1] = acc[2] = acc[3] = make_float4(0.f, 0.f, 0.f, 0.f);

  for (int k0 = 0; k0 < INP; k0 += 16) {
    float4 xv = *(const float4*)(xsrc + k0);
    float4 wv = *(const float4*)(wsrc + k0);
    Xs[lk + 0][lrow] = xv.x; Xs[lk + 1][lrow] = xv.y;
    Xs[lk + 2][lrow] = xv.z; Xs[lk + 3][lrow] = xv.w;
    Ws[lk + 0][lrow] = wv.x; Ws[lk + 1][lrow] = wv.y;
    Ws[lk + 2][lrow] = wv.z; Ws[lk + 3][lrow] = wv.w;
    __syncthreads();
#pragma unroll
    for (int kk = 0; kk < 16; kk++) {
      float4 xa = *(const float4*)&Xs[kk][ty * 4];
      float4 wb = *(const float4*)&Ws[kk][tx * 4];
      acc[0].x = fmaf(xa.x, wb.x, acc[0].x); acc[0].y = fmaf(xa.x, wb.y, acc[0].y);
      acc[0].z = fmaf(xa.x, wb.z, acc[0].z); acc[0].w = fmaf(xa.x, wb.w, acc[0].w);
      acc[1].x = fmaf(xa.y, wb.x, acc[1].x); acc[1].y = fmaf(xa.y, wb.y, acc[1].y);
      acc[1].z = fmaf(xa.y, wb.z, acc[1].z); acc[1].w = fmaf(xa.y, wb.w, acc[1].w);
      acc[2].x = fmaf(xa.z, wb.x, acc[2].x); acc[2].y = fmaf(xa.z, wb.y, acc[2].y);
      acc[2].z = fmaf(xa.z, wb.z, acc[2].z); acc[2].w = fmaf(xa.z, wb.w, acc[2].w);
      acc[3].x = fmaf(xa.w, wb.x, acc[3].x); acc[3].y = fmaf(xa.w, wb.y, acc[3].y);
      acc[3].z = fmaf(xa.w, wb.z, acc[3].z); acc[3].w = fmaf(xa.w, wb.w, acc[3].w);
    }
    __syncthreads();
  }

  float4 bv = *(const float4*)(bias + i0 + tx * 4);
#pragma unroll
  for (int a = 0; a < 4; a++) {
    float4 v = acc[a];
    v.x += bv.x; v.y += bv.y; v.z += bv.z; v.w += bv.w;
    ushort4 o = make_ushort4(f2bf(v.x), f2bf(v.y), f2bf(v.z), f2bf(v.w));
    *(ushort4*)&U[(size_t)(t0 + ty * 4 + a) * HID + i0 + tx * 4] = o;
  }
}

// ---------------------------------------------------------------------------
// Phase 2: persistent recurrent kernel, 2-level dataflow flags (all at IC).
// Producer b sets member flag mf[group(b)][slot(b)] = t+1 after data is acked.
// Group leader (wave 0) polls its 32 member flags (one 256B sector), then
// forwards one group flag gf[group]. Consumers (wave 0) poll only the 8
// group flags; other waves wait at __syncthreads. Staging layout tid+m*256:
// coalesced global, bank-conflict-free LDS.
// ---------------------------------------------------------------------------
__global__ __launch_bounds__(256, 1) void gru_rnn(
    const u16* __restrict__ U0, const u16* __restrict__ U1, const u16* __restrict__ U2,
    const float* __restrict__ Wz, const float* __restrict__ Wr, const float* __restrict__ Wh,
    float* __restrict__ h_g, float* __restrict__ rh_g,
    unsigned* __restrict__ mfh, unsigned* __restrict__ mfr,
    unsigned* __restrict__ gfh, unsigned* __restrict__ gfr,
    float* __restrict__ out)
{
  __shared__ __align__(16) u16  w_s[3][RPB][HID];  // 96 KB bf16 recurrent weights
  __shared__ __align__(16) float h_s[HID];          // 8 KB
  __shared__ __align__(16) float rh_s[HID];         // 8 KB
  __shared__ __align__(16) float hn_s[RPB];
  __shared__ u16  u_s[24];

  const int tid  = threadIdx.x;
  const int lane = tid & 63;
  const int wv   = tid >> 6;
  const int b    = blockIdx.x;
  const int i0   = b * RPB;
  const int grp  = b >> 5;          // group id 0..7
  const int slot = b & 31;          // member slot
  const bool leader = (slot == 0);

  // ---- one-time: recurrent weight rows (cols 0..HID) into LDS as bf16
  {
    const float* Wm[3] = {Wz, Wr, Wh};
    const int c0 = tid * 8;
    for (int m = 0; m < 3; m++) {
      for (int r = 0; r < RPB; r++) {
        const float* src = Wm[m] + (size_t)(i0 + r) * CONC;
        u16* dst = &w_s[m][r][0];
        float4 v0 = *(const float4*)(src + c0);
        float4 v1 = *(const float4*)(src + c0 + 4);
        *(ushort4*)(dst + c0)     = make_ushort4(f2bf(v0.x), f2bf(v0.y), f2bf(v0.z), f2bf(v0.w));
        *(ushort4*)(dst + c0 + 4) = make_ushort4(f2bf(v1.x), f2bf(v1.y), f2bf(v1.z), f2bf(v1.w));
      }
    }
  }

  // ---- U prefetch (threads 0..23: gate = tid>>3, row = tid&7)
  const u16* Ug[3] = {U0, U1, U2};
  const int pg = tid >> 3, pr = tid & 7;
  u16 u_next = 0;
  if (tid < 24) u_next = Ug[pg][(size_t)0 * HID + i0 + pr];

  float z_reg[2] = {0.f, 0.f};

  for (int t = 0; t < SEQ; ++t) {
    const float* hsrc = h_g + (size_t)(t & 1) * HID;         // h_{t-1}
    float*       hdst = h_g + (size_t)((t + 1) & 1) * HID;   // h_t
    float*       rhb  = rh_g + (size_t)(t & 1) * HID;

    // ---- wait for h_{t-1}: wave 0 polls the 8 group flags
    if (wv == 0) {
      const unsigned tgt = (unsigned)t;
      for (;;) {
        unsigned v = cloadu(&gfh[lane & 7]);
        if (__all((int)(v >= tgt))) break;
        __builtin_amdgcn_s_sleep(1);
      }
    }
    asm volatile("" ::: "memory");
    __syncthreads();

    // ---- stage h (coalesced, bank-conflict-free: indices tid + m*256)
    {
      float hv8[8];
#pragma unroll
      for (int m = 0; m < 8; m++) hv8[m] = cload(&hsrc[tid + m * 256]);
#pragma unroll
      for (int m = 0; m < 8; m++) h_s[tid + m * 256] = hv8[m];
    }
    if (tid < 24) u_s[tid] = u_next;
    __syncthreads();
    if (tid < 24) {                       // prefetch next step's U
      const int tn = (t + 1 < SEQ) ? (t + 1) : (SEQ - 1);
      u_next = Ug[pg][(size_t)tn * HID + i0 + pr];
    }

    float4 hv[8];
#pragma unroll
    for (int j = 0; j < 8; j++) hv[j] = ((const float4*)h_s)[j * 64 + lane];

    // ---- r rows (2 per wave), publish rh early
#pragma unroll
    for (int q = 0; q < 2; q++) {
      const int r = wv * 2 + q;
      const u16* wrow = &w_s[1][r][0];
      float acc = 0.f;
#pragma unroll
      for (int j = 0; j < 8; j++) {
        uint2 p = ((const uint2*)wrow)[j * 64 + lane];
        float4 hh = hv[j];
        acc = fmaf(bfl(p.x), hh.x, acc);
        acc = fmaf(bfh(p.x), hh.y, acc);
        acc = fmaf(bfl(p.y), hh.z, acc);
        acc = fmaf(bfh(p.y), hh.w, acc);
      }
#pragma unroll
      for (int o = 32; o; o >>= 1) acc += __shfl_xor(acc, o);
      if (lane == 0) {
        const float a = acc + bf2f(u_s[8 + r]);
        const float s = 1.f / (1.f + __expf(-a));
        cstore(&rhb[i0 + r], s * h_s[i0 + r]);
      }
    }
    asm volatile("s_waitcnt vmcnt(0)" ::: "memory");  // rh at coherent point
    __syncthreads();
    if (tid == 0) cstoreu(&mfr[grp * 64 + slot], (unsigned)(t + 1));
    if (leader && wv == 0) {                          // forward group flag
      const unsigned tgt = (unsigned)(t + 1);
      for (;;) {
        unsigned v = cloadu(&mfr[grp * 64 + (lane & 31)]);
        if (__all((int)(v >= tgt))) break;
      }
      if (lane == 0) cstoreu(&gfr[grp], tgt);
    }

    // ---- z rows (overlap the rh round trip)
#pragma unroll
    for (int q = 0; q < 2; q++) {
      const int r = wv * 2 + q;
      const u16* wrow = &w_s[0][r][0];
      float acc = 0.f;
#pragma unroll
      for (int j = 0; j < 8; j++) {
        uint2 p = ((const uint2*)wrow)[j * 64 + lane];
        float4 hh = hv[j];
        acc = fmaf(bfl(p.x), hh.x, acc);
        acc = fmaf(bfh(p.x), hh.y, acc);
        acc = fmaf(bfl(p.y), hh.z, acc);
        acc = fmaf(bfh(p.y), hh.w, acc);
      }
#pragma unroll
      for (int o = 32; o; o >>= 1) acc += __shfl_xor(acc, o);
      if (lane == 0) {
        const float a = acc + bf2f(u_s[0 + r]);
        z_reg[q] = 1.f / (1.f + __expf(-a));
      }
    }

    // ---- wait for rh: wave 0 polls the 8 group flags
    if (wv == 0) {
      const unsigned tgt = (unsigned)(t + 1);
      for (;;) {
        unsigned v = cloadu(&gfr[lane & 7]);
        if (__all((int)(v >= tgt))) break;
        __builtin_amdgcn_s_sleep(1);
      }
    }
    asm volatile("" ::: "memory");
    __syncthreads();

    // ---- stage rh (coalesced, conflict-free)
    {
      float rv8[8];
#pragma unroll
      for (int m = 0; m < 8; m++) rv8[m] = cload(&rhb[tid + m * 256]);
#pragma unroll
      for (int m = 0; m < 8; m++) rh_s[tid + m * 256] = rv8[m];
    }
    __syncthreads();

    // ---- phase B: h~ rows, 2 per wave
    float4 rv[8];
#pragma unroll
    for (int j = 0; j < 8; j++) rv[j] = ((const float4*)rh_s)[j * 64 + lane];

#pragma unroll
    for (int q = 0; q < 2; q++) {
      const int r = wv * 2 + q;
      const u16* wrow = &w_s[2][r][0];
      float acc = 0.f;
#pragma unroll
      for (int j = 0; j < 8; j++) {
        uint2 p = ((const uint2*)wrow)[j * 64 + lane];
        float4 hh = rv[j];
        acc = fmaf(bfl(p.x), hh.x, acc);
        acc = fmaf(bfh(p.x), hh.y, acc);
        acc = fmaf(bfl(p.y), hh.z, acc);
        acc = fmaf(bfh(p.y), hh.w, acc);
      }
#pragma unroll
      for (int o = 32; o; o >>= 1) acc += __shfl_xor(acc, o);
      if (lane == 0) {
        const float a  = acc + bf2f(u_s[16 + r]);
        const float ht = tanhf(a);
        const float z  = z_reg[q];
        const int i = i0 + r;
        const float hn = (1.f - z) * h_s[i] + z * ht;
        hn_s[r] = hn;
        cstore(&hdst[i], hn);
      }
    }
    asm volatile("s_waitcnt vmcnt(0)" ::: "memory");  // h at coherent point
    __syncthreads();                                   // hn_s visible too
    if (tid == 0) cstoreu(&mfh[grp * 64 + slot], (unsigned)(t + 1));
    if (leader && wv == 0) {                          // forward group flag
      const unsigned tgt = (unsigned)(t + 1);
      for (;;) {
        unsigned v = cloadu(&mfh[grp * 64 + (lane & 31)]);
        if (__all((int)(v >= tgt))) break;
      }
      if (lane == 0) cstoreu(&gfh[grp], tgt);
    }
    if (tid < 2) {                                     // plain stores; host-only reader
      float4 v = ((const float4*)hn_s)[tid];
      *(float4*)&out[(size_t)t * HID + i0 + tid * 4] = v;
      if (t == SEQ - 1)
        *(float4*)&out[(size_t)SEQ * HID + i0 + tid * 4] = v;   // h_final
    }
  }
}

// ---------------------------------------------------------------------------
extern "C" void kernel_launch(void* const* d_in, const int* in_sizes, int n_in,
                              void* d_out, int out_size, void* d_ws, size_t ws_size,
                              hipStream_t stream)
{
  const float* X  = (const float*)d_in[0];
  const float* Wz = (const float*)d_in[1];
  const float* bz = (const float*)d_in[2];
  const float* Wr = (const float*)d_in[3];
  const float* br = (const float*)d_in[4];
  const float* Wh = (const float*)d_in[5];
  const float* bh = (const float*)d_in[6];
  float* out = (float*)d_out;

  char* ws = (char*)d_ws;
  const size_t SZ_U = (size_t)SEQ * HID * sizeof(u16);   // 32 MB per gate
  u16* Uz = (u16*)(ws);
  u16* Ur = (u16*)(ws + SZ_U);
  u16* Uh = (u16*)(ws + 2 * SZ_U);
  float* h_g   = (float*)(ws + 3 * SZ_U);                // [2][HID]
  float* rh_g  = h_g + 2 * HID;                          // [2][HID]
  unsigned* mfh = (unsigned*)(rh_g + 2 * HID);           // [NG][64] padded
  unsigned* mfr = mfh + NG * 64;                         // [NG][64]
  unsigned* gfh = mfr + NG * 64;                         // [16] (8 used)
  unsigned* gfr = gfh + 16;                              // [16]

  // zero h/rh buffers, member flags, group flags
  const size_t ctrl_bytes = (size_t)4 * HID * 4 + (2 * NG * 64 + 32) * 4;
  hipMemsetAsync(ws + 3 * SZ_U, 0, ctrl_bytes, stream);

  gru_gemm<<<dim3(HID / 64, SEQ / 64, 3), 256, 0, stream>>>(
      X, Wz, Wr, Wh, bz, br, bh, Uz, Ur, Uh);

  gru_rnn<<<dim3(NBLK), dim3(256), 0, stream>>>(
      Uz, Ur, Uh, Wz, Wr, Wh, h_g, rh_g, mfh, mfr, gfh, gfr, out);
}